// Round 4
// baseline (252.927 us; speedup 1.0000x reference)
//
#include <hip/hip_runtime.h>
#include <hip/hip_cooperative_groups.h>

namespace cg = cooperative_groups;

constexpr int BB   = 4;
constexpr int CCH  = 256;
constexpr int IDIM = 128;
constexpr int NAa  = 4096;
constexpr int NDd  = 16384;
constexpr int PAD  = 320;                 // aug dim 257 padded to 320
constexpr float NAinv = 1.0f / 4096.0f;

typedef __bf16 bf16x8 __attribute__((ext_vector_type(8)));
typedef float  f32x4  __attribute__((ext_vector_type(4)));

__device__ inline unsigned short f2bfu(float f) {
    unsigned u = __float_as_uint(f);
    u += 0x7FFFu + ((u >> 16) & 1u);      // RNE
    return (unsigned short)(u >> 16);
}

struct Par {
    const float* aim; const float* qw; const float* gw; const float* gb;
    const float* thw; const float* thb; const float* phw; const float* phb;
    const float* qb; const float* gamma; const float* beta; const float* mean; const float* var;
    const float* detect; float* out;
    unsigned short* Abf; float* r; float* Spart;
    unsigned short* Shat; unsigned short* Ph; unsigned short* Rt; unsigned short* Th; unsigned short* W5;
    float* b5;
};

template<int PHASE> __device__ inline void gsync() {
    if constexpr (PHASE < 0) cg::this_grid().sync();
}

// One cooperative kernel, grid 512 x 512 threads (2 blocks/CU co-resident).
// PHASE < 0: all phases with grid syncs (cooperative). PHASE = n: phase n only (fallback).
template<int PHASE>
__global__ __launch_bounds__(512, 4) void k_mega(Par p) {
    __shared__ __align__(16) char smraw[32768];   // union: P0 red(2KB) / P1 sred(32KB) / P5 lb(20KB)
    const int bid = blockIdx.x, t = threadIdx.x;
    const int wv = t >> 6, lane = t & 63, quad = lane >> 4, l16 = lane & 15;

    // ================= P0: aim->bf16 + rowsum; Phat/RhatT prep =================
    if (PHASE < 0 || PHASE == 0) {
        {   // conv: rows 2*bid (threads 0..255) and 2*bid+1 (threads 256..511)
            const int half = t >> 8, tt = t & 255;
            const int row = bid * 2 + half;
            const float* src = p.aim + (long)row * NAa;
            unsigned short* dst = p.Abf + (long)row * NAa;
            float s = 0.f;
            #pragma unroll
            for (int j = 0; j < 4; ++j) {
                const int e = (j * 256 + tt) * 4;
                float4 v = *(const float4*)(src + e);
                s += v.x + v.y + v.z + v.w;
                ushort4 o; o.x = f2bfu(v.x); o.y = f2bfu(v.y); o.z = f2bfu(v.z); o.w = f2bfu(v.w);
                *(ushort4*)(dst + e) = o;
            }
            float* red = (float*)smraw;
            red[t] = s; __syncthreads();
            for (int st_ = 128; st_ > 0; st_ >>= 1) {
                if (tt < st_) red[half * 256 + tt] += red[half * 256 + tt + st_];
                __syncthreads();
            }
            if (tt == 0) p.r[row] = red[half * 256];
        }
        {   // prep: 184320 elements over 512*512 threads (single pass)
            const int idx = bid * 512 + t;
            if (idx < CCH * PAD) {
                const int o = idx / PAD, c = idx - o * PAD;
                float acc = 0.f;
                if (c <= 256) {
                    for (int i = 0; i < IDIM; ++i)
                        acc += p.qw[o * IDIM + i] * ((c < 256) ? p.gw[i * CCH + c] : p.gb[i]);
                }
                p.Ph[idx] = f2bfu(acc);
            } else if (idx < CCH * PAD + PAD * PAD) {
                const int id2 = idx - CCH * PAD;
                const int c2 = id2 / PAD, k = id2 - c2 * PAD;   // row c2, col k (transposed)
                float acc = 0.f;
                if (k <= 256 && c2 <= 256) {
                    for (int i = 0; i < IDIM; ++i) {
                        const float av = (k < 256) ? p.thw[i * CCH + k] : p.thb[i];
                        const float bv = (c2 < 256) ? p.phw[i * CCH + c2] : p.phb[i];
                        acc += av * bv;
                    }
                }
                p.Rt[id2] = f2bfu(acc);
            }
        }
    }
    gsync<PHASE>();

    // ================= P1: S partials. 512 blocks = 16 tiles x 8 chunks x 4 b. =================
    // All 8 waves split the K=512 chunk (2 ks-steps each), LDS tree-reduce, wave 0 writes.
    if (PHASE < 0 || PHASE == 1) {
        const int z = bid >> 4, rem = bid & 15;
        const int b = z >> 3;
        const unsigned short* A = p.Abf + (long)b * CCH * NAa;
        const int mb = (rem >> 2) * 64, nbb = (rem & 3) * 64;
        const int kb = (z & 7) * 512;
        f32x4 acc[4][4] = {};
        #pragma unroll
        for (int s = 0; s < 2; ++s) {
            const int k = kb + (wv * 2 + s) * 32 + quad * 8;
            bf16x8 af[4], bfr[4];
            #pragma unroll
            for (int i = 0; i < 4; ++i) af[i]  = *(const bf16x8*)(A + (long)(mb + i * 16 + l16) * NAa + k);
            #pragma unroll
            for (int j = 0; j < 4; ++j) bfr[j] = *(const bf16x8*)(A + (long)(nbb + j * 16 + l16) * NAa + k);
            #pragma unroll
            for (int i = 0; i < 4; ++i)
                #pragma unroll
                for (int j = 0; j < 4; ++j)
                    acc[i][j] = __builtin_amdgcn_mfma_f32_16x16x32_bf16(af[i], bfr[j], acc[i][j], 0, 0, 0);
        }
        float* sred = (float*)smraw;          // 2 regions x 4096 f32
        auto lput = [&](int rg) {
            #pragma unroll
            for (int i = 0; i < 4; ++i)
                #pragma unroll
                for (int j = 0; j < 4; ++j)
                    #pragma unroll
                    for (int rr = 0; rr < 4; ++rr)
                        sred[rg * 4096 + ((i * 4 + j) * 4 + rr) * 64 + lane] = acc[i][j][rr];
        };
        auto ladd = [&](int rg) {
            #pragma unroll
            for (int i = 0; i < 4; ++i)
                #pragma unroll
                for (int j = 0; j < 4; ++j)
                    #pragma unroll
                    for (int rr = 0; rr < 4; ++rr)
                        acc[i][j][rr] += sred[rg * 4096 + ((i * 4 + j) * 4 + rr) * 64 + lane];
        };
        if (wv == 4 || wv == 5) lput(wv - 4);
        __syncthreads();
        if (wv == 0 || wv == 1) ladd(wv);
        __syncthreads();
        if (wv == 6 || wv == 7) lput(wv - 6);
        __syncthreads();
        if (wv == 2 || wv == 3) ladd(wv - 2);
        __syncthreads();
        if (wv == 2 || wv == 3) lput(wv - 2);
        __syncthreads();
        if (wv == 0 || wv == 1) ladd(wv);
        __syncthreads();
        if (wv == 1) lput(0);
        __syncthreads();
        if (wv == 0) {
            ladd(0);
            float* o = p.Spart + (long)z * CCH * CCH;
            #pragma unroll
            for (int i = 0; i < 4; ++i)
                #pragma unroll
                for (int j = 0; j < 4; ++j)
                    #pragma unroll
                    for (int reg = 0; reg < 4; ++reg)
                        o[(long)(mb + i * 16 + quad * 4 + reg) * CCH + nbb + j * 16 + l16] = acc[i][j][reg];
        }
    }
    gsync<PHASE>();

    // ================= P2: assemble Shat (320x320 bf16, symmetric) =================
    if (PHASE < 0 || PHASE == 2) {
        for (int e = bid * 512 + t; e < BB * PAD * PAD; e += 512 * 512) {
            const int b = e / (PAD * PAD), idx = e - b * (PAD * PAD);
            const int k = idx / PAD, n = idx - k * PAD;
            float v = 0.f;
            if (k < 256 && n < 256) {
                #pragma unroll
                for (int pp = 0; pp < 8; ++pp)
                    v += p.Spart[(long)(b * 8 + pp) * CCH * CCH + k * CCH + n];
            } else if (k == 256 && n < 256) v = p.r[b * CCH + n];
            else if (n == 256 && k < 256)   v = p.r[b * CCH + k];
            else if (k == 256 && n == 256)  v = 4096.0f;
            p.Shat[(long)b * PAD * PAD + idx] = f2bfu(v);
        }
    }
    gsync<PHASE>();

    // ================= P3: That = Phat @ Shat (80 wave-tasks, spread over blocks) =================
    if (PHASE < 0 || PHASE == 3) {
        if (wv == 0 && (bid % 6) == 0 && (bid / 6) < 80) {
            const int tid = bid / 6;
            const int b = tid / 20, rem2 = tid % 20;
            const int n0 = (rem2 % 5) * 64, m0 = (rem2 / 5) * 64;
            const unsigned short* S = p.Shat + (long)b * PAD * PAD;
            unsigned short* T = p.Th + (long)b * CCH * PAD;
            f32x4 acc[4][4] = {};
            for (int kt = 0; kt < PAD; kt += 32) {
                bf16x8 af[4], bfr[4];
                #pragma unroll
                for (int i = 0; i < 4; ++i) af[i]  = *(const bf16x8*)(p.Ph + (long)(m0 + i * 16 + l16) * PAD + kt + quad * 8);
                #pragma unroll
                for (int j = 0; j < 4; ++j) bfr[j] = *(const bf16x8*)(S + (long)(n0 + j * 16 + l16) * PAD + kt + quad * 8);
                #pragma unroll
                for (int i = 0; i < 4; ++i)
                    #pragma unroll
                    for (int j = 0; j < 4; ++j)
                        acc[i][j] = __builtin_amdgcn_mfma_f32_16x16x32_bf16(af[i], bfr[j], acc[i][j], 0, 0, 0);
            }
            #pragma unroll
            for (int i = 0; i < 4; ++i)
                #pragma unroll
                for (int j = 0; j < 4; ++j)
                    #pragma unroll
                    for (int reg = 0; reg < 4; ++reg)
                        T[(long)(m0 + i * 16 + quad * 4 + reg) * PAD + n0 + j * 16 + l16] = f2bfu(acc[i][j][reg]);
        }
    }
    gsync<PHASE>();

    // ================= P4: W5 = diag(s)/Na*(That@Rhat)+I ; col 256 -> b5 =================
    if (PHASE < 0 || PHASE == 4) {
        if (wv == 0 && (bid % 6) == 0 && (bid / 6) < 80) {
            const int tid = bid / 6;
            const int b = tid / 20, rem2 = tid % 20;
            const int n0 = (rem2 % 5) * 64, m0 = (rem2 / 5) * 64;
            const unsigned short* A = p.Th + (long)b * CCH * PAD;
            f32x4 acc[4][4] = {};
            for (int kt = 0; kt < PAD; kt += 32) {
                bf16x8 af[4], bfr[4];
                #pragma unroll
                for (int i = 0; i < 4; ++i) af[i]  = *(const bf16x8*)(A + (long)(m0 + i * 16 + l16) * PAD + kt + quad * 8);
                #pragma unroll
                for (int j = 0; j < 4; ++j) bfr[j] = *(const bf16x8*)(p.Rt + (long)(n0 + j * 16 + l16) * PAD + kt + quad * 8);
                #pragma unroll
                for (int i = 0; i < 4; ++i)
                    #pragma unroll
                    for (int j = 0; j < 4; ++j)
                        acc[i][j] = __builtin_amdgcn_mfma_f32_16x16x32_bf16(af[i], bfr[j], acc[i][j], 0, 0, 0);
            }
            #pragma unroll
            for (int i = 0; i < 4; ++i) {
                #pragma unroll
                for (int reg = 0; reg < 4; ++reg) {
                    const int o = m0 + i * 16 + quad * 4 + reg;
                    const float s = p.gamma[o] * rsqrtf(p.var[o] + 1e-5f);
                    #pragma unroll
                    for (int j = 0; j < 4; ++j) {
                        const int c2 = n0 + j * 16 + l16;
                        const float val = acc[i][j][reg] * s * NAinv;
                        if (c2 < CCH)
                            p.W5[((long)b * CCH + o) * CCH + c2] = f2bfu(val + (o == c2 ? 1.0f : 0.0f));
                        else if (c2 == CCH)
                            p.b5[b * CCH + o] = val + s * (p.qb[o] - p.mean[o]) + p.beta[o];
                    }
                }
            }
        }
    }
    gsync<PHASE>();

    // ================= P5: out = W5 @ detect + b5 (R3 k_final body, 512 blocks) =================
    if (PHASE < 0 || PHASE == 5) {
        const int z = bid >> 7;
        const int nb = (bid & 127) * 128;
        const float* D = p.detect + (long)z * CCH * NDd;
        float* O = p.out + (long)z * CCH * NDd;
        const unsigned short* W = p.W5 + (long)z * CCH * CCH;
        const int mw = (wv >> 1) * 64, nw = (wv & 1) * 64;
        const int r2 = t >> 4, g = t & 15;
        const bool st = (t < 256);
        auto lb = (unsigned short (*)[128][40])smraw;   // lb[2][128][40], 20 KB

        f32x4 xa[4], xb[4];
        bf16x8 af2[2][4], bfr[4];

        auto load_tile = [&](f32x4* x, int kt) {
            const float* base = D + (long)(kt + 2 * r2) * NDd + nb + 8 * g;
            x[0] = *(const f32x4*)(base);
            x[1] = *(const f32x4*)(base + NDd);
            x[2] = *(const f32x4*)(base + 4);
            x[3] = *(const f32x4*)(base + NDd + 4);
        };
        auto write_tile = [&](int buf, const f32x4* x) {
            #pragma unroll
            for (int e2 = 0; e2 < 2; ++e2)
                #pragma unroll
                for (int c = 0; c < 4; ++c) {
                    const int n = 8 * g + 4 * e2 + c;
                    const int pp = ((n & 7) << 4) + (n >> 3);
                    const unsigned v = (unsigned)f2bfu(x[2 * e2][c]) |
                                       ((unsigned)f2bfu(x[2 * e2 + 1][c]) << 16);
                    *(unsigned*)&lb[buf][pp][2 * r2] = v;
                }
        };
        auto loadW = [&](bf16x8* a, int kt) {
            #pragma unroll
            for (int i = 0; i < 4; ++i)
                a[i] = *(const bf16x8*)(W + (long)(mw + i * 16 + l16) * CCH + kt + quad * 8);
        };

        int pj[4];
        #pragma unroll
        for (int j = 0; j < 4; ++j) {
            const int n = nw + j * 16 + l16;
            pj[j] = ((n & 7) << 4) + (n >> 3);
        }

        f32x4 acc[4][4] = {};
        __syncthreads();                      // smraw handoff from earlier phases
        if (st) { load_tile(xa, 0); load_tile(xb, 32); }
        loadW(af2[0], 0);
        if (st) { write_tile(0, xa); load_tile(xa, 64); }
        #pragma unroll
        for (int it = 0; it < 8; ++it) {
            __syncthreads();
            const int kt = it * 32;
            #pragma unroll
            for (int j = 0; j < 4; ++j)
                bfr[j] = *(const bf16x8*)&lb[it & 1][pj[j]][quad * 8];
            #pragma unroll
            for (int i = 0; i < 4; ++i)
                #pragma unroll
                for (int j = 0; j < 4; ++j)
                    acc[i][j] = __builtin_amdgcn_mfma_f32_16x16x32_bf16(af2[it & 1][i], bfr[j], acc[i][j], 0, 0, 0);
            if (it < 7) {
                loadW(af2[(it + 1) & 1], kt + 32);
                if (st) {
                    write_tile((it + 1) & 1, (it & 1) ? xa : xb);
                    if (it < 5) load_tile((it & 1) ? xa : xb, (it + 3) * 32);
                }
            }
        }
        #pragma unroll
        for (int i = 0; i < 4; ++i) {
            float bv[4];
            #pragma unroll
            for (int reg = 0; reg < 4; ++reg)
                bv[reg] = p.b5[z * CCH + mw + i * 16 + quad * 4 + reg];
            #pragma unroll
            for (int j = 0; j < 4; ++j) {
                const int n = nb + nw + j * 16 + l16;
                #pragma unroll
                for (int reg = 0; reg < 4; ++reg)
                    O[(long)(mw + i * 16 + quad * 4 + reg) * NDd + n] = acc[i][j][reg] + bv[reg];
            }
        }
    }
}

extern "C" void kernel_launch(void* const* d_in, const int* in_sizes, int n_in,
                              void* d_out, int out_size, void* d_ws, size_t ws_size,
                              hipStream_t stream) {
    float* ws = (float*)d_ws;
    unsigned short* Abf = (unsigned short*)ws;              // 4,194,304 us
    float* r     = ws + 2097152;                            // 1,024
    float* Spart = r + 1024;                                // 2,097,152 f
    unsigned short* ub = (unsigned short*)(Spart + 2097152);
    unsigned short* Shat_u  = ub;                           // 409,600 us
    unsigned short* Phat_u  = Shat_u + 409600;              //  81,920 us
    unsigned short* RhatT_u = Phat_u + 81920;               // 102,400 us
    unsigned short* That_u  = RhatT_u + 102400;             // 327,680 us
    unsigned short* W5u     = That_u + 327680;              // 262,144 us
    float* b5 = (float*)(W5u + 262144);                     // 1,024 f

    Par pp;
    pp.aim    = (const float*)d_in[1];
    pp.qw     = (const float*)d_in[8];
    pp.gw     = (const float*)d_in[2];
    pp.gb     = (const float*)d_in[3];
    pp.thw    = (const float*)d_in[4];
    pp.thb    = (const float*)d_in[5];
    pp.phw    = (const float*)d_in[6];
    pp.phb    = (const float*)d_in[7];
    pp.qb     = (const float*)d_in[9];
    pp.gamma  = (const float*)d_in[10];
    pp.beta   = (const float*)d_in[11];
    pp.mean   = (const float*)d_in[12];
    pp.var    = (const float*)d_in[13];
    pp.detect = (const float*)d_in[0];
    pp.out    = (float*)d_out;
    pp.Abf = Abf; pp.r = r; pp.Spart = Spart;
    pp.Shat = Shat_u; pp.Ph = Phat_u; pp.Rt = RhatT_u; pp.Th = That_u; pp.W5 = W5u;
    pp.b5 = b5;

    static int occ = -1;
    if (occ < 0) {
        if (hipOccupancyMaxActiveBlocksPerMultiprocessor(&occ, k_mega<-1>, 512, 0) != hipSuccess)
            occ = 0;
    }
    if (occ >= 2) {
        void* args[] = { (void*)&pp };
        hipLaunchCooperativeKernel(k_mega<-1>, dim3(512), dim3(512), args, 0, stream);
    } else {
        k_mega<0><<<dim3(512), dim3(512), 0, stream>>>(pp);
        k_mega<1><<<dim3(512), dim3(512), 0, stream>>>(pp);
        k_mega<2><<<dim3(512), dim3(512), 0, stream>>>(pp);
        k_mega<3><<<dim3(512), dim3(512), 0, stream>>>(pp);
        k_mega<4><<<dim3(512), dim3(512), 0, stream>>>(pp);
        k_mega<5><<<dim3(512), dim3(512), 0, stream>>>(pp);
    }
}

// Round 5
// 232.014 us; speedup vs baseline: 1.0901x; 1.0901x over previous
//
#include <hip/hip_runtime.h>
#include <hip/hip_cooperative_groups.h>

namespace cg = cooperative_groups;

constexpr int BB   = 4;
constexpr int CCH  = 256;
constexpr int IDIM = 128;
constexpr int NAa  = 4096;
constexpr int NDd  = 16384;
constexpr int PAD  = 320;                 // aug dim 257 padded to 320
constexpr float NAinv = 1.0f / 4096.0f;
constexpr int NBLK = 256;                 // grid: 256 blocks x 512 thr, 1 block/CU

typedef __bf16 bf16x8 __attribute__((ext_vector_type(8)));
typedef float  f32x4  __attribute__((ext_vector_type(4)));

__device__ inline unsigned short f2bfu(float f) {
    unsigned u = __float_as_uint(f);
    u += 0x7FFFu + ((u >> 16) & 1u);      // RNE
    return (unsigned short)(u >> 16);
}

struct Par {
    const float* aim; const float* qw; const float* gw; const float* gb;
    const float* thw; const float* thb; const float* phw; const float* phb;
    const float* qb; const float* gamma; const float* beta; const float* mean; const float* var;
    const float* detect; float* out;
    unsigned short* Abf; float* r; float* Spart;
    unsigned short* Shat; unsigned short* Ph; unsigned short* Rt; unsigned short* Th; unsigned short* W5;
    float* b5;
};

template<int PHASE> __device__ inline void gsync() {
    if constexpr (PHASE < 0) cg::this_grid().sync();
}

// v2: 256 blocks x 512 thr, launch_bounds(512,2) -> 1 block/CU, reg cap 256 (NO spills;
// R4's (512,4) capped at 128 combined and spilled every MFMA phase: VGPR=64, +85MB scratch).
template<int PHASE>
__global__ __launch_bounds__(512, 2) void k_mega(Par p) {
    __shared__ __align__(16) char smraw[32768];   // union: P0 red(2KB) / P1 sred(32KB) / P5 lb(20KB)
    const int bid = blockIdx.x, t = threadIdx.x;
    const int wv = t >> 6, lane = t & 63, quad = lane >> 4, l16 = lane & 15;

    // ================= P0: aim->bf16 + rowsum (4 rows/block); Phat/RhatT prep =================
    if (PHASE < 0 || PHASE == 0) {
        {   // conv: rows bid*4 + half*2 + rr, halves of 256 threads
            const int half = t >> 8, tt = t & 255;
            float* red = (float*)smraw;
            #pragma unroll
            for (int rr = 0; rr < 2; ++rr) {
                const int row = bid * 4 + half * 2 + rr;
                const float* src = p.aim + (long)row * NAa;
                unsigned short* dst = p.Abf + (long)row * NAa;
                float s = 0.f;
                #pragma unroll
                for (int j = 0; j < 4; ++j) {
                    const int e = (j * 256 + tt) * 4;
                    float4 v = *(const float4*)(src + e);
                    s += v.x + v.y + v.z + v.w;
                    ushort4 o; o.x = f2bfu(v.x); o.y = f2bfu(v.y); o.z = f2bfu(v.z); o.w = f2bfu(v.w);
                    *(ushort4*)(dst + e) = o;
                }
                __syncthreads();              // red reuse guard (rr loop)
                red[t] = s; __syncthreads();
                for (int st_ = 128; st_ > 0; st_ >>= 1) {
                    if (tt < st_) red[half * 256 + tt] += red[half * 256 + tt + st_];
                    __syncthreads();
                }
                if (tt == 0) p.r[row] = red[half * 256];
            }
        }
        // prep: 184320 elements, grid-stride over 131072 threads
        for (int idx = bid * 512 + t; idx < CCH * PAD + PAD * PAD; idx += NBLK * 512) {
            if (idx < CCH * PAD) {
                const int o = idx / PAD, c = idx - o * PAD;
                float acc = 0.f;
                if (c <= 256) {
                    for (int i = 0; i < IDIM; ++i)
                        acc += p.qw[o * IDIM + i] * ((c < 256) ? p.gw[i * CCH + c] : p.gb[i]);
                }
                p.Ph[idx] = f2bfu(acc);
            } else {
                const int id2 = idx - CCH * PAD;
                const int c2 = id2 / PAD, k = id2 - c2 * PAD;   // row c2, col k (transposed)
                float acc = 0.f;
                if (k <= 256 && c2 <= 256) {
                    for (int i = 0; i < IDIM; ++i) {
                        const float av = (k < 256) ? p.thw[i * CCH + k] : p.thb[i];
                        const float bv = (c2 < 256) ? p.phw[i * CCH + c2] : p.phb[i];
                        acc += av * bv;
                    }
                }
                p.Rt[id2] = f2bfu(acc);
            }
        }
    }
    gsync<PHASE>();

    // ================= P1: S partials. 512 tasks = 16 tiles x 8 chunks x 4 b; 2 per block. =================
    // All 8 waves split the K=512 chunk (2 ks-steps each), LDS tree-reduce, wave 0 writes.
    if (PHASE < 0 || PHASE == 1) {
        float* sred = (float*)smraw;          // 2 regions x 4096 f32
        #pragma unroll
        for (int s2 = 0; s2 < 2; ++s2) {
            const int task = s2 * NBLK + bid;
            const int z = task >> 4, rem = task & 15;
            const int b = z >> 3;
            const unsigned short* A = p.Abf + (long)b * CCH * NAa;
            const int mb = (rem >> 2) * 64, nbb = (rem & 3) * 64;
            const int kb = (z & 7) * 512;
            f32x4 acc[4][4] = {};
            #pragma unroll
            for (int s = 0; s < 2; ++s) {
                const int k = kb + (wv * 2 + s) * 32 + quad * 8;
                bf16x8 af[4], bfr[4];
                #pragma unroll
                for (int i = 0; i < 4; ++i) af[i]  = *(const bf16x8*)(A + (long)(mb + i * 16 + l16) * NAa + k);
                #pragma unroll
                for (int j = 0; j < 4; ++j) bfr[j] = *(const bf16x8*)(A + (long)(nbb + j * 16 + l16) * NAa + k);
                #pragma unroll
                for (int i = 0; i < 4; ++i)
                    #pragma unroll
                    for (int j = 0; j < 4; ++j)
                        acc[i][j] = __builtin_amdgcn_mfma_f32_16x16x32_bf16(af[i], bfr[j], acc[i][j], 0, 0, 0);
            }
            auto lput = [&](int rg) {
                #pragma unroll
                for (int i = 0; i < 4; ++i)
                    #pragma unroll
                    for (int j = 0; j < 4; ++j)
                        #pragma unroll
                        for (int rr = 0; rr < 4; ++rr)
                            sred[rg * 4096 + ((i * 4 + j) * 4 + rr) * 64 + lane] = acc[i][j][rr];
            };
            auto ladd = [&](int rg) {
                #pragma unroll
                for (int i = 0; i < 4; ++i)
                    #pragma unroll
                    for (int j = 0; j < 4; ++j)
                        #pragma unroll
                        for (int rr = 0; rr < 4; ++rr)
                            acc[i][j][rr] += sred[rg * 4096 + ((i * 4 + j) * 4 + rr) * 64 + lane];
            };
            __syncthreads();                  // sred reuse guard (s2 loop)
            if (wv == 4 || wv == 5) lput(wv - 4);
            __syncthreads();
            if (wv == 0 || wv == 1) ladd(wv);
            __syncthreads();
            if (wv == 6 || wv == 7) lput(wv - 6);
            __syncthreads();
            if (wv == 2 || wv == 3) ladd(wv - 2);
            __syncthreads();
            if (wv == 2 || wv == 3) lput(wv - 2);
            __syncthreads();
            if (wv == 0 || wv == 1) ladd(wv);
            __syncthreads();
            if (wv == 1) lput(0);
            __syncthreads();
            if (wv == 0) {
                ladd(0);
                float* o = p.Spart + (long)z * CCH * CCH;
                #pragma unroll
                for (int i = 0; i < 4; ++i)
                    #pragma unroll
                    for (int j = 0; j < 4; ++j)
                        #pragma unroll
                        for (int reg = 0; reg < 4; ++reg)
                            o[(long)(mb + i * 16 + quad * 4 + reg) * CCH + nbb + j * 16 + l16] = acc[i][j][reg];
            }
        }
    }
    gsync<PHASE>();

    // ================= P2: assemble Shat (320x320 bf16, symmetric) =================
    if (PHASE < 0 || PHASE == 2) {
        for (int e = bid * 512 + t; e < BB * PAD * PAD; e += NBLK * 512) {
            const int b = e / (PAD * PAD), idx = e - b * (PAD * PAD);
            const int k = idx / PAD, n = idx - k * PAD;
            float v = 0.f;
            if (k < 256 && n < 256) {
                #pragma unroll
                for (int pp = 0; pp < 8; ++pp)
                    v += p.Spart[(long)(b * 8 + pp) * CCH * CCH + k * CCH + n];
            } else if (k == 256 && n < 256) v = p.r[b * CCH + n];
            else if (n == 256 && k < 256)   v = p.r[b * CCH + k];
            else if (k == 256 && n == 256)  v = 4096.0f;
            p.Shat[(long)b * PAD * PAD + idx] = f2bfu(v);
        }
    }
    gsync<PHASE>();

    // ================= P3: That = Phat @ Shat. 160 wave-tasks (32x64 tiles), 160 CUs. =================
    if (PHASE < 0 || PHASE == 3) {
        if (wv == 0 && bid < 160) {
            const int b = bid / 40, rem2 = bid % 40;
            const int m0 = (rem2 / 5) * 32, n0 = (rem2 % 5) * 64;
            const unsigned short* S = p.Shat + (long)b * PAD * PAD;
            unsigned short* T = p.Th + (long)b * CCH * PAD;
            f32x4 acc[2][4] = {};
            for (int kt = 0; kt < PAD; kt += 32) {
                bf16x8 af[2], bfr[4];
                #pragma unroll
                for (int i = 0; i < 2; ++i) af[i]  = *(const bf16x8*)(p.Ph + (long)(m0 + i * 16 + l16) * PAD + kt + quad * 8);
                #pragma unroll
                for (int j = 0; j < 4; ++j) bfr[j] = *(const bf16x8*)(S + (long)(n0 + j * 16 + l16) * PAD + kt + quad * 8);
                #pragma unroll
                for (int i = 0; i < 2; ++i)
                    #pragma unroll
                    for (int j = 0; j < 4; ++j)
                        acc[i][j] = __builtin_amdgcn_mfma_f32_16x16x32_bf16(af[i], bfr[j], acc[i][j], 0, 0, 0);
            }
            #pragma unroll
            for (int i = 0; i < 2; ++i)
                #pragma unroll
                for (int j = 0; j < 4; ++j)
                    #pragma unroll
                    for (int reg = 0; reg < 4; ++reg)
                        T[(long)(m0 + i * 16 + quad * 4 + reg) * PAD + n0 + j * 16 + l16] = f2bfu(acc[i][j][reg]);
        }
    }
    gsync<PHASE>();

    // ================= P4: W5 = diag(s)/Na*(That@Rhat)+I ; col 256 -> b5. 160 wave-tasks. =================
    if (PHASE < 0 || PHASE == 4) {
        if (wv == 0 && bid < 160) {
            const int b = bid / 40, rem2 = bid % 40;
            const int m0 = (rem2 / 5) * 32, n0 = (rem2 % 5) * 64;
            const unsigned short* A = p.Th + (long)b * CCH * PAD;
            f32x4 acc[2][4] = {};
            for (int kt = 0; kt < PAD; kt += 32) {
                bf16x8 af[2], bfr[4];
                #pragma unroll
                for (int i = 0; i < 2; ++i) af[i]  = *(const bf16x8*)(A + (long)(m0 + i * 16 + l16) * PAD + kt + quad * 8);
                #pragma unroll
                for (int j = 0; j < 4; ++j) bfr[j] = *(const bf16x8*)(p.Rt + (long)(n0 + j * 16 + l16) * PAD + kt + quad * 8);
                #pragma unroll
                for (int i = 0; i < 2; ++i)
                    #pragma unroll
                    for (int j = 0; j < 4; ++j)
                        acc[i][j] = __builtin_amdgcn_mfma_f32_16x16x32_bf16(af[i], bfr[j], acc[i][j], 0, 0, 0);
            }
            #pragma unroll
            for (int i = 0; i < 2; ++i) {
                #pragma unroll
                for (int reg = 0; reg < 4; ++reg) {
                    const int o = m0 + i * 16 + quad * 4 + reg;
                    const float s = p.gamma[o] * rsqrtf(p.var[o] + 1e-5f);
                    #pragma unroll
                    for (int j = 0; j < 4; ++j) {
                        const int c2 = n0 + j * 16 + l16;
                        const float val = acc[i][j][reg] * s * NAinv;
                        if (c2 < CCH)
                            p.W5[((long)b * CCH + o) * CCH + c2] = f2bfu(val + (o == c2 ? 1.0f : 0.0f));
                        else if (c2 == CCH)
                            p.b5[b * CCH + o] = val + s * (p.qb[o] - p.mean[o]) + p.beta[o];
                    }
                }
            }
        }
    }
    gsync<PHASE>();

    // ================= P5: out = W5 @ detect + b5. 512 tile-tasks, 2 per block. =================
    if (PHASE < 0 || PHASE == 5) {
        const int mw = (wv >> 1) * 64, nw = (wv & 1) * 64;
        const int r2 = t >> 4, g = t & 15;
        const bool st = (t < 256);
        auto lb = (unsigned short (*)[128][40])smraw;   // lb[2][128][40], 20 KB

        int pj[4];
        #pragma unroll
        for (int j = 0; j < 4; ++j) {
            const int n = nw + j * 16 + l16;
            pj[j] = ((n & 7) << 4) + (n >> 3);
        }

        #pragma unroll
        for (int s2 = 0; s2 < 2; ++s2) {
            const int task = s2 * NBLK + bid;
            const int z = task >> 7;
            const int nb = (task & 127) * 128;
            const float* D = p.detect + (long)z * CCH * NDd;
            float* O = p.out + (long)z * CCH * NDd;
            const unsigned short* W = p.W5 + (long)z * CCH * CCH;

            f32x4 xa[4], xb[4];
            bf16x8 af2[2][4], bfr[4];

            auto load_tile = [&](f32x4* x, int kt) {
                const float* base = D + (long)(kt + 2 * r2) * NDd + nb + 8 * g;
                x[0] = *(const f32x4*)(base);
                x[1] = *(const f32x4*)(base + NDd);
                x[2] = *(const f32x4*)(base + 4);
                x[3] = *(const f32x4*)(base + NDd + 4);
            };
            auto write_tile = [&](int buf, const f32x4* x) {
                #pragma unroll
                for (int e2 = 0; e2 < 2; ++e2)
                    #pragma unroll
                    for (int c = 0; c < 4; ++c) {
                        const int n = 8 * g + 4 * e2 + c;
                        const int pp = ((n & 7) << 4) + (n >> 3);
                        const unsigned v = (unsigned)f2bfu(x[2 * e2][c]) |
                                           ((unsigned)f2bfu(x[2 * e2 + 1][c]) << 16);
                        *(unsigned*)&lb[buf][pp][2 * r2] = v;
                    }
            };
            auto loadW = [&](bf16x8* a, int kt) {
                #pragma unroll
                for (int i = 0; i < 4; ++i)
                    a[i] = *(const bf16x8*)(W + (long)(mw + i * 16 + l16) * CCH + kt + quad * 8);
            };

            f32x4 acc[4][4] = {};
            __syncthreads();                  // lb reuse guard (s2 loop / earlier phases)
            if (st) { load_tile(xa, 0); load_tile(xb, 32); }
            loadW(af2[0], 0);
            if (st) { write_tile(0, xa); load_tile(xa, 64); }
            #pragma unroll
            for (int it = 0; it < 8; ++it) {
                __syncthreads();
                const int kt = it * 32;
                #pragma unroll
                for (int j = 0; j < 4; ++j)
                    bfr[j] = *(const bf16x8*)&lb[it & 1][pj[j]][quad * 8];
                #pragma unroll
                for (int i = 0; i < 4; ++i)
                    #pragma unroll
                    for (int j = 0; j < 4; ++j)
                        acc[i][j] = __builtin_amdgcn_mfma_f32_16x16x32_bf16(af2[it & 1][i], bfr[j], acc[i][j], 0, 0, 0);
                if (it < 7) {
                    loadW(af2[(it + 1) & 1], kt + 32);
                    if (st) {
                        write_tile((it + 1) & 1, (it & 1) ? xa : xb);
                        if (it < 5) load_tile((it & 1) ? xa : xb, (it + 3) * 32);
                    }
                }
            }
            #pragma unroll
            for (int i = 0; i < 4; ++i) {
                float bv[4];
                #pragma unroll
                for (int reg = 0; reg < 4; ++reg)
                    bv[reg] = p.b5[z * CCH + mw + i * 16 + quad * 4 + reg];
                #pragma unroll
                for (int j = 0; j < 4; ++j) {
                    const int n = nb + nw + j * 16 + l16;
                    #pragma unroll
                    for (int reg = 0; reg < 4; ++reg)
                        O[(long)(mw + i * 16 + quad * 4 + reg) * NDd + n] = acc[i][j][reg] + bv[reg];
                }
            }
        }
    }
}

extern "C" void kernel_launch(void* const* d_in, const int* in_sizes, int n_in,
                              void* d_out, int out_size, void* d_ws, size_t ws_size,
                              hipStream_t stream) {
    float* ws = (float*)d_ws;
    unsigned short* Abf = (unsigned short*)ws;              // 4,194,304 us
    float* r     = ws + 2097152;                            // 1,024
    float* Spart = r + 1024;                                // 2,097,152 f
    unsigned short* ub = (unsigned short*)(Spart + 2097152);
    unsigned short* Shat_u  = ub;                           // 409,600 us
    unsigned short* Phat_u  = Shat_u + 409600;              //  81,920 us
    unsigned short* RhatT_u = Phat_u + 81920;               // 102,400 us
    unsigned short* That_u  = RhatT_u + 102400;             // 327,680 us
    unsigned short* W5u     = That_u + 327680;              // 262,144 us
    float* b5 = (float*)(W5u + 262144);                     // 1,024 f

    Par pp;
    pp.aim    = (const float*)d_in[1];
    pp.qw     = (const float*)d_in[8];
    pp.gw     = (const float*)d_in[2];
    pp.gb     = (const float*)d_in[3];
    pp.thw    = (const float*)d_in[4];
    pp.thb    = (const float*)d_in[5];
    pp.phw    = (const float*)d_in[6];
    pp.phb    = (const float*)d_in[7];
    pp.qb     = (const float*)d_in[9];
    pp.gamma  = (const float*)d_in[10];
    pp.beta   = (const float*)d_in[11];
    pp.mean   = (const float*)d_in[12];
    pp.var    = (const float*)d_in[13];
    pp.detect = (const float*)d_in[0];
    pp.out    = (float*)d_out;
    pp.Abf = Abf; pp.r = r; pp.Spart = Spart;
    pp.Shat = Shat_u; pp.Ph = Phat_u; pp.Rt = RhatT_u; pp.Th = That_u; pp.W5 = W5u;
    pp.b5 = b5;

    static int occ = -1;
    if (occ < 0) {
        if (hipOccupancyMaxActiveBlocksPerMultiprocessor(&occ, k_mega<-1>, 512, 0) != hipSuccess)
            occ = 0;
    }
    if (occ >= 1) {
        void* args[] = { (void*)&pp };
        hipLaunchCooperativeKernel(k_mega<-1>, dim3(NBLK), dim3(512), args, 0, stream);
    } else {
        k_mega<0><<<dim3(NBLK), dim3(512), 0, stream>>>(pp);
        k_mega<1><<<dim3(NBLK), dim3(512), 0, stream>>>(pp);
        k_mega<2><<<dim3(NBLK), dim3(512), 0, stream>>>(pp);
        k_mega<3><<<dim3(NBLK), dim3(512), 0, stream>>>(pp);
        k_mega<4><<<dim3(NBLK), dim3(512), 0, stream>>>(pp);
        k_mega<5><<<dim3(NBLK), dim3(512), 0, stream>>>(pp);
    }
}